// Round 3
// baseline (440.340 us; speedup 1.0000x reference)
//
#include <hip/hip_runtime.h>

// BasePointPWL: out[n,c] = interp of x[n,c] in per-channel PWL table (xp, yp), K=64, C=64.
//
// v3b (v3 with native vector type for nontemporal builtins — HIP_vector_type rejected):
//  - 4-deep explicit load pipeline (4 float4 loads in flight; was unroll-2).
//  - Nontemporal loads/stores for the 268+268 MB zero-reuse streams (nt flag, no L2 alloc).
//  - VALU trim: v = fmaf(x,31.5,31.5) is the grid coordinate; clamp in float domain;
//    s = (int)clamped (trunc==floor since >=0); frac = (v - s)*K1, K1 = dx/(dx+1e-7).
//    Reproduces reference exactly in all branches (below-range, interior, above-range).
//  - Y-only LDS table [c][65] (16.6 KB -> 8 blocks/CU); gather y[b+s],y[b+s+1] -> ds_read2_b32;
//    bank = (c+s)%32, data-random s -> ~2-way avg (free).

#define C_CH 64
#define K_PT 64
#define LDK  65

typedef float f32x4 __attribute__((ext_vector_type(4)));

__global__ __launch_bounds__(256, 8) void pwl_kernel(
    const float* __restrict__ x,
    const float* __restrict__ yp,
    float* __restrict__ out,
    unsigned int total)  // N*C = 67108864
{
    __shared__ float s_y[C_CH * LDK];  // 16,640 B

    const int t = threadIdx.x;

    // Stage yp (16 KB) with coalesced 16B reads.
    {
        const f32x4* yp4 = reinterpret_cast<const f32x4*>(yp);
        #pragma unroll
        for (int i = 0; i < 4; ++i) {
            int jf = t + i * 256;            // float4 index, 0..1023
            f32x4 v = yp4[jf];
            int j  = jf << 2;
            int cc = j >> 6;
            int kk = j & 63;                 // 4-aligned, row never crossed
            float* dst = &s_y[cc * LDK + kk];
            dst[0] = v.x; dst[1] = v.y; dst[2] = v.z; dst[3] = v.w;
        }
    }
    __syncthreads();

    const float K1 = (2.0f / 63.0f) / (2.0f / 63.0f + 1e-7f);  // dx * INV

    const unsigned int total4  = total >> 2;
    const unsigned int stride4 = gridDim.x * blockDim.x;  // multiple of 16 -> channels invariant
    unsigned int g = blockIdx.x * blockDim.x + (unsigned)t;

    const int cbase = (int)((g << 2) & 63u);
    const int b0 = (cbase + 0) * LDK;
    const int b1 = (cbase + 1) * LDK;
    const int b2 = (cbase + 2) * LDK;
    const int b3 = (cbase + 3) * LDK;

    const f32x4* __restrict__ x4 = reinterpret_cast<const f32x4*>(x);
    f32x4* __restrict__ o4       = reinterpret_cast<f32x4*>(out);

    // One quad: coordinate -> clamped segment -> ds_read2 gather -> lerp.
    #define PROC(xv, R)                                                          \
        {                                                                        \
            float v0 = fmaf((xv).x, 31.5f, 31.5f);                               \
            float v1 = fmaf((xv).y, 31.5f, 31.5f);                               \
            float v2 = fmaf((xv).z, 31.5f, 31.5f);                               \
            float v3 = fmaf((xv).w, 31.5f, 31.5f);                               \
            float f0 = fminf(62.0f, fmaxf(0.0f, v0));                            \
            float f1 = fminf(62.0f, fmaxf(0.0f, v1));                            \
            float f2 = fminf(62.0f, fmaxf(0.0f, v2));                            \
            float f3 = fminf(62.0f, fmaxf(0.0f, v3));                            \
            int s0 = (int)f0, s1 = (int)f1, s2 = (int)f2, s3 = (int)f3;          \
            const float* p0 = &s_y[b0 + s0];                                     \
            const float* p1 = &s_y[b1 + s1];                                     \
            const float* p2 = &s_y[b2 + s2];                                     \
            const float* p3 = &s_y[b3 + s3];                                     \
            float ya0 = p0[0], yb0 = p0[1];                                      \
            float ya1 = p1[0], yb1 = p1[1];                                      \
            float ya2 = p2[0], yb2 = p2[1];                                      \
            float ya3 = p3[0], yb3 = p3[1];                                      \
            (R).x = fmaf((v0 - (float)s0) * K1, yb0 - ya0, ya0);                 \
            (R).y = fmaf((v1 - (float)s1) * K1, yb1 - ya1, ya1);                 \
            (R).z = fmaf((v2 - (float)s2) * K1, yb2 - ya2, ya2);                 \
            (R).w = fmaf((v3 - (float)s3) * K1, yb3 - ya3, ya3);                 \
        }

    // Main loop: 4 independent 16B loads in flight, then process+store each quad.
    for (; g + 3u * stride4 < total4; g += 4u * stride4) {
        f32x4 xa = __builtin_nontemporal_load(&x4[g]);
        f32x4 xb = __builtin_nontemporal_load(&x4[g + stride4]);
        f32x4 xc = __builtin_nontemporal_load(&x4[g + 2u * stride4]);
        f32x4 xd = __builtin_nontemporal_load(&x4[g + 3u * stride4]);

        f32x4 ra, rb, rc, rd;
        PROC(xa, ra);
        __builtin_nontemporal_store(ra, &o4[g]);
        PROC(xb, rb);
        __builtin_nontemporal_store(rb, &o4[g + stride4]);
        PROC(xc, rc);
        __builtin_nontemporal_store(rc, &o4[g + 2u * stride4]);
        PROC(xd, rd);
        __builtin_nontemporal_store(rd, &o4[g + 3u * stride4]);
    }
    // 16B tail.
    for (; g < total4; g += stride4) {
        f32x4 xv = __builtin_nontemporal_load(&x4[g]);
        f32x4 r;
        PROC(xv, r);
        __builtin_nontemporal_store(r, &o4[g]);
    }
    #undef PROC

    // Scalar tail for total % 4 != 0 (not hit for 2^26; kept for safety).
    if (blockIdx.x == 0 && (unsigned)t < (total & 3u)) {
        unsigned int f = (total & ~3u) + (unsigned)t;
        int c = (int)(f & 63u);
        float xv = x[f];
        float v = fmaf(xv, 31.5f, 31.5f);
        float fv = fminf(62.0f, fmaxf(0.0f, v));
        int s = (int)fv;
        float ya = s_y[c * LDK + s];
        float yb = s_y[c * LDK + s + 1];
        out[f] = fmaf((v - (float)s) * K1, yb - ya, ya);
    }
}

extern "C" void kernel_launch(void* const* d_in, const int* in_sizes, int n_in,
                              void* d_out, int out_size, void* d_ws, size_t ws_size,
                              hipStream_t stream) {
    const float* x  = (const float*)d_in[0];
    // d_in[1] = xp: unused (uniform linspace grid, handled analytically)
    const float* yp = (const float*)d_in[2];
    float* out = (float*)d_out;
    unsigned int total = (unsigned int)in_sizes[0];  // N*C = 67108864

    const int block = 256;
    const int grid  = 2048;  // 8 blocks/CU x 256 CUs; 8 macro-iters (32 float4) per thread
    pwl_kernel<<<grid, block, 0, stream>>>(x, yp, out, total);
}

// Round 4
// 432.370 us; speedup vs baseline: 1.0184x; 1.0184x over previous
//
#include <hip/hip_runtime.h>

// BasePointPWL: out[n,c] = interp of x[n,c] in per-channel PWL table (xp, yp), K=64, C=64.
//
// v4 (post-mortem r3: nt flag + manual 4-deep pipeline regressed v2 by ~5% — nt bypasses
// the L2 buffering the 6.5 TB/s fill kernels use; manual store interleave pinned a worse
// schedule than the compiler's). Revert to v2 memory structure, keep the v3 VALU trim:
//  - Plain (cached) float4 loads/stores, #pragma unroll 4, compiler-scheduled.
//  - v = fmaf(x,31.5,31.5) is the grid coordinate; clamp in float domain;
//    s = (int)clamped (trunc==floor since >=0); frac = (v - s)*K1, K1 = dx/(dx+1e-7).
//    Reproduces the reference exactly in all branches (below-range, interior, above).
//  - Y-only LDS table [c][65] (16.6 KB -> 8 blocks/CU, full occupancy);
//    gather y[b+s],y[b+s+1] -> single ds_read2_b32; bank=(c+s)%32, random s -> ~2-way.

#define C_CH 64
#define K_PT 64
#define LDK  65

typedef float f32x4 __attribute__((ext_vector_type(4)));

__global__ __launch_bounds__(256, 8) void pwl_kernel(
    const float* __restrict__ x,
    const float* __restrict__ yp,
    float* __restrict__ out,
    unsigned int total)  // N*C = 67108864
{
    __shared__ float s_y[C_CH * LDK];  // 16,640 B

    const int t = threadIdx.x;

    // Stage yp (16 KB) with coalesced 16B reads.
    {
        const f32x4* yp4 = reinterpret_cast<const f32x4*>(yp);
        #pragma unroll
        for (int i = 0; i < 4; ++i) {
            int jf = t + i * 256;            // float4 index, 0..1023
            f32x4 v = yp4[jf];
            int j  = jf << 2;
            int cc = j >> 6;
            int kk = j & 63;                 // 4-aligned, row never crossed
            float* dst = &s_y[cc * LDK + kk];
            dst[0] = v.x; dst[1] = v.y; dst[2] = v.z; dst[3] = v.w;
        }
    }
    __syncthreads();

    const float K1 = (2.0f / 63.0f) / (2.0f / 63.0f + 1e-7f);  // dx * INV

    const unsigned int total4  = total >> 2;
    const unsigned int stride4 = gridDim.x * blockDim.x;  // multiple of 16 -> channels invariant
    unsigned int g = blockIdx.x * blockDim.x + (unsigned)t;

    // Channels of this thread's 4 elements are invariant across the grid-stride loop.
    const int cbase = (int)((g << 2) & 63u);   // in {0,4,...,60}
    const int b0 = (cbase + 0) * LDK;
    const int b1 = (cbase + 1) * LDK;
    const int b2 = (cbase + 2) * LDK;
    const int b3 = (cbase + 3) * LDK;

    const f32x4* __restrict__ x4 = reinterpret_cast<const f32x4*>(x);
    f32x4* __restrict__ o4       = reinterpret_cast<f32x4*>(out);

    #pragma unroll 4
    for (; g < total4; g += stride4) {
        f32x4 xv = x4[g];

        // Grid coordinate; clamp in float domain; trunc == floor (value >= 0).
        float v0 = fmaf(xv.x, 31.5f, 31.5f);
        float v1 = fmaf(xv.y, 31.5f, 31.5f);
        float v2 = fmaf(xv.z, 31.5f, 31.5f);
        float v3 = fmaf(xv.w, 31.5f, 31.5f);
        float f0 = fminf(62.0f, fmaxf(0.0f, v0));
        float f1 = fminf(62.0f, fmaxf(0.0f, v1));
        float f2 = fminf(62.0f, fmaxf(0.0f, v2));
        float f3 = fminf(62.0f, fmaxf(0.0f, v3));
        int s0 = (int)f0, s1 = (int)f1, s2 = (int)f2, s3 = (int)f3;

        const float* p0 = &s_y[b0 + s0];
        const float* p1 = &s_y[b1 + s1];
        const float* p2 = &s_y[b2 + s2];
        const float* p3 = &s_y[b3 + s3];
        float ya0 = p0[0], yb0 = p0[1];   // -> ds_read2_b32
        float ya1 = p1[0], yb1 = p1[1];
        float ya2 = p2[0], yb2 = p2[1];
        float ya3 = p3[0], yb3 = p3[1];

        f32x4 r;
        r.x = fmaf((v0 - (float)s0) * K1, yb0 - ya0, ya0);
        r.y = fmaf((v1 - (float)s1) * K1, yb1 - ya1, ya1);
        r.z = fmaf((v2 - (float)s2) * K1, yb2 - ya2, ya2);
        r.w = fmaf((v3 - (float)s3) * K1, yb3 - ya3, ya3);

        o4[g] = r;
    }

    // Scalar tail for total % 4 != 0 (not hit for 2^26; kept for safety).
    if (blockIdx.x == 0 && (unsigned)t < (total & 3u)) {
        unsigned int f = (total & ~3u) + (unsigned)t;
        int c = (int)(f & 63u);
        float xv = x[f];
        float v = fmaf(xv, 31.5f, 31.5f);
        float fv = fminf(62.0f, fmaxf(0.0f, v));
        int s = (int)fv;
        float ya = s_y[c * LDK + s];
        float yb = s_y[c * LDK + s + 1];
        out[f] = fmaf((v - (float)s) * K1, yb - ya, ya);
    }
}

extern "C" void kernel_launch(void* const* d_in, const int* in_sizes, int n_in,
                              void* d_out, int out_size, void* d_ws, size_t ws_size,
                              hipStream_t stream) {
    const float* x  = (const float*)d_in[0];
    // d_in[1] = xp: unused (uniform linspace grid, handled analytically)
    const float* yp = (const float*)d_in[2];
    float* out = (float*)d_out;
    unsigned int total = (unsigned int)in_sizes[0];  // N*C = 67108864

    const int block = 256;
    const int grid  = 2048;  // 8 blocks/CU x 256 CUs resident in one shot; 32 float4/thread
    pwl_kernel<<<grid, block, 0, stream>>>(x, yp, out, total);
}